// Round 2
// 851.745 us; speedup vs baseline: 1.0379x; 1.0379x over previous
//
#include <hip/hip_runtime.h>

typedef __bf16 bf16_t;
typedef __bf16 bf16x2 __attribute__((ext_vector_type(2)));
typedef __bf16 bf16x4 __attribute__((ext_vector_type(4)));
typedef __bf16 bf16x8 __attribute__((ext_vector_type(8)));
typedef float floatx4 __attribute__((ext_vector_type(4)));

#define MFMA16(a, b, c) __builtin_amdgcn_mfma_f32_16x16x32_bf16((a), (b), (c), 0, 0, 0)

__global__ void detect_kernel(const uint4* __restrict__ q, int* __restrict__ flag)
{
    __shared__ int cnt;
    if (threadIdx.x == 0) cnt = 0;
    __syncthreads();
    int local = 0;
    // 65536 u16 = 8192 uint4
    for (int i = threadIdx.x; i < 8192; i += 1024) {
        uint4 u = q[i];
        unsigned w;
        w = u.x; if ((w & 0x7F80u) == 0x7F80u) local++; if (((w >> 16) & 0x7F80u) == 0x7F80u) local++;
        w = u.y; if ((w & 0x7F80u) == 0x7F80u) local++; if (((w >> 16) & 0x7F80u) == 0x7F80u) local++;
        w = u.z; if ((w & 0x7F80u) == 0x7F80u) local++; if (((w >> 16) & 0x7F80u) == 0x7F80u) local++;
        w = u.w; if ((w & 0x7F80u) == 0x7F80u) local++; if (((w >> 16) & 0x7F80u) == 0x7F80u) local++;
    }
    atomicAdd(&cnt, local);
    __syncthreads();
    if (threadIdx.x == 0) flag[0] = (cnt >= 8) ? 1 : 0;
}

__device__ inline void cvt16_f32(const float* __restrict__ p, bf16x8& lo, bf16x8& hi)
{
    float4 a = ((const float4*)p)[0];
    float4 b = ((const float4*)p)[1];
    float4 c = ((const float4*)p)[2];
    float4 d = ((const float4*)p)[3];
    lo[0] = (bf16_t)a.x; lo[1] = (bf16_t)a.y; lo[2] = (bf16_t)a.z; lo[3] = (bf16_t)a.w;
    lo[4] = (bf16_t)b.x; lo[5] = (bf16_t)b.y; lo[6] = (bf16_t)b.z; lo[7] = (bf16_t)b.w;
    hi[0] = (bf16_t)c.x; hi[1] = (bf16_t)c.y; hi[2] = (bf16_t)c.z; hi[3] = (bf16_t)c.w;
    hi[4] = (bf16_t)d.x; hi[5] = (bf16_t)d.y; hi[6] = (bf16_t)d.z; hi[7] = (bf16_t)d.w;
}

// ---------------------------------------------------------------------------
// Merged projection GEMM (unchanged).
// ---------------------------------------------------------------------------
__global__ __launch_bounds__(256) void proj_kernel(
    const void* __restrict__ query, const void* __restrict__ lcr,
    const void* __restrict__ qw, const void* __restrict__ kw,
    const void* __restrict__ vw,
    const void* __restrict__ qbias, const void* __restrict__ kbias,
    const void* __restrict__ vbias,
    bf16_t* __restrict__ q_ws, bf16_t* __restrict__ k_ws,
    bf16_t* __restrict__ vt_ws, bf16_t* __restrict__ km_ws,
    bf16_t* __restrict__ vmt_ws, const int* __restrict__ flag)
{
    __shared__ __attribute__((aligned(16))) bf16_t As[128 * 40];
    __shared__ __attribute__((aligned(16))) bf16_t Bs[128 * 40];

    const int f32 = flag[0];
    const int K = 1024;
    const int blk = blockIdx.x;

    int rm0, wcol, mode, Tdim;
    float scale;
    const void* Xv; size_t xoff0; const void* Wv; const void* biasv; bf16_t* Yv;
    if (blk < 768) {
        rm0 = (blk & 31) * 128;
        const int cn0 = (blk >> 5) * 128;
        const int sel = cn0 >> 10;
        wcol = cn0 & 1023;
        Xv = query; xoff0 = 0; Tdim = 2048;
        if (sel == 0)      { Wv = qw; biasv = qbias; Yv = q_ws;  mode = 1; scale = 0.125f; }
        else if (sel == 1) { Wv = kw; biasv = kbias; Yv = k_ws;  mode = 1; scale = 1.f; }
        else               { Wv = vw; biasv = vbias; Yv = vt_ws; mode = 2; scale = 1.f; }
    } else if (blk < 896) {
        const int b2 = blk - 768;
        rm0 = (b2 & 15) * 128; wcol = (b2 >> 4) * 128;
        Xv = lcr; xoff0 = 0;
        Wv = kw; biasv = kbias; Yv = km_ws; mode = 1; scale = 1.f; Tdim = 1024;
    } else {
        const int b2 = blk - 896;
        rm0 = (b2 & 15) * 128; wcol = (b2 >> 4) * 128;
        Xv = lcr; xoff0 = (size_t)1024 * 2 * 1024;
        Wv = vw; biasv = vbias; Yv = vmt_ws; mode = 2; scale = 1.f; Tdim = 1024;
    }

    const int tid = threadIdx.x;
    const int wvid = tid >> 6, lane = tid & 63;
    const int qd = lane >> 4, l16 = lane & 15;
    const int wm = (wvid >> 1) * 64, wn = (wvid & 1) * 64;

    const int srow = tid >> 1;
    const int sseg = (tid & 1) * 16;
    const size_t xoff = xoff0 + (size_t)(rm0 + srow) * K + sseg;
    const size_t woff = (size_t)(wcol + srow) * K + sseg;
    const bf16_t* Xh = (const bf16_t*)Xv + xoff;
    const float*  Xf = (const float*)Xv + xoff;
    const bf16_t* Wh = (const bf16_t*)Wv + woff;
    const float*  Wf = (const float*)Wv + woff;
    bf16_t* Asw = &As[srow * 40 + sseg];
    bf16_t* Bsw = &Bs[srow * 40 + sseg];

    floatx4 acc[4][4];
#pragma unroll
    for (int i = 0; i < 4; i++)
#pragma unroll
        for (int j = 0; j < 4; j++) acc[i][j] = (floatx4){0.f, 0.f, 0.f, 0.f};

    for (int k0 = 0; k0 < K; k0 += 32) {
        bf16x8 x0, x1, w0, w1;
        if (f32) {
            cvt16_f32(Xf + k0, x0, x1);
            cvt16_f32(Wf + k0, w0, w1);
        } else {
            x0 = *(const bf16x8*)(Xh + k0);
            x1 = *(const bf16x8*)(Xh + k0 + 8);
            w0 = *(const bf16x8*)(Wh + k0);
            w1 = *(const bf16x8*)(Wh + k0 + 8);
        }
        __syncthreads();
        *(bf16x8*)(Asw) = x0;
        *(bf16x8*)(Asw + 8) = x1;
        *(bf16x8*)(Bsw) = w0;
        *(bf16x8*)(Bsw + 8) = w1;
        __syncthreads();

        bf16x8 af[4], bfg[4];
#pragma unroll
        for (int mi = 0; mi < 4; mi++)
            af[mi] = *(const bf16x8*)(&As[(wm + mi * 16 + l16) * 40 + qd * 8]);
#pragma unroll
        for (int ni = 0; ni < 4; ni++)
            bfg[ni] = *(const bf16x8*)(&Bs[(wn + ni * 16 + l16) * 40 + qd * 8]);
#pragma unroll
        for (int mi = 0; mi < 4; mi++)
#pragma unroll
            for (int ni = 0; ni < 4; ni++)
                acc[mi][ni] = MFMA16(af[mi], bfg[ni], acc[mi][ni]);
    }

#pragma unroll
    for (int ni = 0; ni < 4; ni++) {
        const int col = wcol + wn + ni * 16 + l16;
        const float bv = f32 ? ((const float*)biasv)[col]
                             : (float)((const bf16_t*)biasv)[col];
        const int hh = col >> 6, dd = col & 63;
#pragma unroll
        for (int mi = 0; mi < 4; mi++) {
            const int row0 = rm0 + wm + mi * 16 + qd * 4;  // always even
            const int t = row0 >> 1;                       // rows: (t,b=0),(t,1),(t+1,0),(t+1,1)
            const float v0 = (acc[mi][ni][0] + bv) * scale;
            const float v1 = (acc[mi][ni][1] + bv) * scale;
            const float v2 = (acc[mi][ni][2] + bv) * scale;
            const float v3 = (acc[mi][ni][3] + bv) * scale;
            if (mode == 1) {
                Yv[(((size_t)hh * Tdim) + t) * 64 + dd]            = (bf16_t)v0;
                Yv[(((size_t)(16 + hh) * Tdim) + t) * 64 + dd]     = (bf16_t)v1;
                Yv[(((size_t)hh * Tdim) + t + 1) * 64 + dd]        = (bf16_t)v2;
                Yv[(((size_t)(16 + hh) * Tdim) + t + 1) * 64 + dd] = (bf16_t)v3;
            } else {
                bf16x2 p0; p0[0] = (bf16_t)v0; p0[1] = (bf16_t)v2;
                bf16x2 p1; p1[0] = (bf16_t)v1; p1[1] = (bf16_t)v3;
                *(bf16x2*)&Yv[((size_t)hh * 64 + dd) * Tdim + t] = p0;
                *(bf16x2*)&Yv[((size_t)(16 + hh) * 64 + dd) * Tdim + t] = p1;
            }
        }
    }
}

// ---------------------------------------------------------------------------
// Barrier-free flash attention, software-pipelined, split into two passes via
// blockIdx.z (z=0: local causal + pos; z=1: memory attention). Each pass
// writes a gated f32 partial; combine_kernel sums them into bf16 att.
// Pipelining: K and pos prefetched one key-block ahead (pos is folded into
// the MFMA C-init, which also makes the causal mask free); V loads issued at
// the top of the iteration so they complete under QK^T + softmax.
// ---------------------------------------------------------------------------
#define PSTR 88

__device__ __forceinline__ void load_k8(bf16x8 k0v[4], bf16x8 k1v[4],
                                        const bf16_t* __restrict__ Kb,
                                        int s0, int l16, int qd)
{
#pragma unroll
    for (int ni = 0; ni < 4; ni++) {
        const bf16_t* p = Kb + (size_t)(s0 + ni * 16 + l16) * 64 + qd * 8;
        k0v[ni] = *(const bf16x8*)p;
        k1v[ni] = *(const bf16x8*)(p + 32);
    }
}

__device__ __forceinline__ void load_pos4(floatx4 pn[4], const float* __restrict__ posf,
                                          const bf16_t* __restrict__ posh, int f32,
                                          int T, int trow_base, int s0, int l16, bool diag)
{
#pragma unroll
    for (int ni = 0; ni < 4; ni++) {
        const int sg = s0 + ni * 16 + l16;
#pragma unroll
        for (int r = 0; r < 4; r++) {
            const int tg = trow_base + r;
            const size_t pidx = (size_t)tg * T + sg;
            float pv = f32 ? posf[pidx] : (float)posh[pidx];
            if (diag && sg > tg) pv = -1e9f;
            pn[ni][r] = pv;
        }
    }
}

__global__ __launch_bounds__(256) void attn_kernel(
    const bf16_t* __restrict__ Qg, const bf16_t* __restrict__ Kg,
    const bf16_t* __restrict__ VTg, const bf16_t* __restrict__ KMg,
    const bf16_t* __restrict__ VMTg, const void* __restrict__ posv,
    const void* __restrict__ mbiasv, float* __restrict__ attl,
    float* __restrict__ attm, const int* __restrict__ flag, int T, int Mlen)
{
    __shared__ __attribute__((aligned(16))) bf16_t Ps[4][16 * PSTR];

    const int f32 = flag[0];
    const int tid = threadIdx.x;
    const int wv = tid >> 6, lane = tid & 63;
    const int qd = lane >> 4, l16 = lane & 15;
    const int qt = blockIdx.x;
    const int y = blockIdx.y;
    const int b = y & 1, h = y >> 1;
    const int bh = b * 16 + h;
    const int tw = qt * 64 + wv * 16;
    const int trow_base = tw + qd * 4;
    bf16_t* Pw = &Ps[wv][0];

    const bf16_t* Qb = Qg + (size_t)bh * T * 64;
    const bf16x8 a0 = *(const bf16x8*)(Qb + (size_t)(tw + l16) * 64 + qd * 8);
    const bf16x8 a1 = *(const bf16x8*)(Qb + (size_t)(tw + l16) * 64 + 32 + qd * 8);

    const float gb = f32 ? ((const float*)mbiasv)[h] : (float)((const bf16_t*)mbiasv)[h];
    const float g = 1.f / (1.f + __expf(-gb));

    floatx4 O[4];
    float ml[4], ll[4];
#pragma unroll
    for (int i = 0; i < 4; i++) {
        O[i] = (floatx4){0.f, 0.f, 0.f, 0.f};
        ml[i] = -1e9f; ll[i] = 0.f;
    }

    bf16x8 kc0[4], kc1[4];

    if (blockIdx.z == 0) {
        // ---- local causal attention + position encoding ----
        const bf16_t* Kb  = Kg  + (size_t)bh * T * 64;
        const bf16_t* VTb = VTg + (size_t)bh * 64 * T;
        const float*  posf = (const float*)posv + (size_t)h * T * T;
        const bf16_t* posh = (const bf16_t*)posv + (size_t)h * T * T;

        floatx4 pn[4];
        load_k8(kc0, kc1, Kb, 0, l16, qd);
        load_pos4(pn, posf, posh, f32, T, trow_base, 0, l16, qt == 0);

        for (int st = 0; st <= qt; ++st) {
            const int s0 = st * 64;
            // V for this key block: issued now, consumed after softmax.
            bf16x8 vf0[4], vf1[4];
#pragma unroll
            for (int ni = 0; ni < 4; ni++) {
                const bf16_t* p = VTb + (size_t)(ni * 16 + l16) * T + s0 + qd * 8;
                vf0[ni] = *(const bf16x8*)p;
                vf1[ni] = *(const bf16x8*)(p + 32);
            }
            // QK^T with pos (and causal mask) pre-loaded as the accumulator.
            floatx4 c[4];
#pragma unroll
            for (int ni = 0; ni < 4; ni++) {
                floatx4 t = pn[ni];
                t = MFMA16(a0, kc0[ni], t);
                t = MFMA16(a1, kc1[ni], t);
                c[ni] = t;
            }
            // Prefetch K + pos for next key block (hidden under softmax + PV).
            if (st < qt) {
                load_k8(kc0, kc1, Kb, s0 + 64, l16, qd);
                load_pos4(pn, posf, posh, f32, T, trow_base, s0 + 64, l16, st + 1 == qt);
            }
            // Online softmax; denominator kept as a per-lane partial (reduced
            // once in the epilogue).
#pragma unroll
            for (int r = 0; r < 4; r++) {
                float mt = fmaxf(fmaxf(c[0][r], c[1][r]), fmaxf(c[2][r], c[3][r]));
                mt = fmaxf(mt, __shfl_xor(mt, 1));
                mt = fmaxf(mt, __shfl_xor(mt, 2));
                mt = fmaxf(mt, __shfl_xor(mt, 4));
                mt = fmaxf(mt, __shfl_xor(mt, 8));
                const float mnew = fmaxf(ml[r], mt);
                const float alpha = __expf(ml[r] - mnew);
                ml[r] = mnew;
                float ls = 0.f;
#pragma unroll
                for (int ni = 0; ni < 4; ni++) {
                    const float p = __expf(c[ni][r] - mnew);
                    c[ni][r] = p;
                    ls += p;
                }
                ll[r] = ll[r] * alpha + ls;
#pragma unroll
                for (int ni = 0; ni < 4; ni++) O[ni][r] *= alpha;
#pragma unroll
                for (int ni = 0; ni < 4; ni++)
                    Pw[(qd * 4 + r) * PSTR + ni * 16 + l16] = (bf16_t)c[ni][r];
            }
            asm volatile("s_waitcnt lgkmcnt(0)" ::: "memory");
            const bf16x8 pf0 = *(const bf16x8*)(&Pw[l16 * PSTR + qd * 8]);
            const bf16x8 pf1 = *(const bf16x8*)(&Pw[l16 * PSTR + 32 + qd * 8]);
#pragma unroll
            for (int ni = 0; ni < 4; ni++) {
                O[ni] = MFMA16(pf0, vf0[ni], O[ni]);
                O[ni] = MFMA16(pf1, vf1[ni], O[ni]);
            }
        }

        const float gl = 1.f - g;
#pragma unroll
        for (int r = 0; r < 4; r++) {
            float lt = ll[r];
            lt += __shfl_xor(lt, 1);
            lt += __shfl_xor(lt, 2);
            lt += __shfl_xor(lt, 4);
            lt += __shfl_xor(lt, 8);
            const int tg = trow_base + r;
            const float inv = gl / lt;
#pragma unroll
            for (int ni = 0; ni < 4; ni++)
                attl[(size_t)(tg * 2 + b) * 1024 + h * 64 + ni * 16 + l16] = O[ni][r] * inv;
        }
    } else {
        // ---- memory attention (no mask, no pos) ----
        const bf16_t* Kb  = KMg  + (size_t)bh * Mlen * 64;
        const bf16_t* VTb = VMTg + (size_t)bh * 64 * Mlen;
        const int nst = Mlen >> 6;

        load_k8(kc0, kc1, Kb, 0, l16, qd);

        for (int st = 0; st < nst; ++st) {
            const int s0 = st * 64;
            bf16x8 vf0[4], vf1[4];
#pragma unroll
            for (int ni = 0; ni < 4; ni++) {
                const bf16_t* p = VTb + (size_t)(ni * 16 + l16) * Mlen + s0 + qd * 8;
                vf0[ni] = *(const bf16x8*)p;
                vf1[ni] = *(const bf16x8*)(p + 32);
            }
            floatx4 c[4];
#pragma unroll
            for (int ni = 0; ni < 4; ni++) {
                floatx4 t = (floatx4){0.f, 0.f, 0.f, 0.f};
                t = MFMA16(a0, kc0[ni], t);
                t = MFMA16(a1, kc1[ni], t);
                c[ni] = t;
            }
            if (st < nst - 1) load_k8(kc0, kc1, Kb, s0 + 64, l16, qd);
#pragma unroll
            for (int r = 0; r < 4; r++) {
                float mt = fmaxf(fmaxf(c[0][r], c[1][r]), fmaxf(c[2][r], c[3][r]));
                mt = fmaxf(mt, __shfl_xor(mt, 1));
                mt = fmaxf(mt, __shfl_xor(mt, 2));
                mt = fmaxf(mt, __shfl_xor(mt, 4));
                mt = fmaxf(mt, __shfl_xor(mt, 8));
                const float mnew = fmaxf(ml[r], mt);
                const float alpha = __expf(ml[r] - mnew);
                ml[r] = mnew;
                float ls = 0.f;
#pragma unroll
                for (int ni = 0; ni < 4; ni++) {
                    const float p = __expf(c[ni][r] - mnew);
                    c[ni][r] = p;
                    ls += p;
                }
                ll[r] = ll[r] * alpha + ls;
#pragma unroll
                for (int ni = 0; ni < 4; ni++) O[ni][r] *= alpha;
#pragma unroll
                for (int ni = 0; ni < 4; ni++)
                    Pw[(qd * 4 + r) * PSTR + ni * 16 + l16] = (bf16_t)c[ni][r];
            }
            asm volatile("s_waitcnt lgkmcnt(0)" ::: "memory");
            const bf16x8 pf0 = *(const bf16x8*)(&Pw[l16 * PSTR + qd * 8]);
            const bf16x8 pf1 = *(const bf16x8*)(&Pw[l16 * PSTR + 32 + qd * 8]);
#pragma unroll
            for (int ni = 0; ni < 4; ni++) {
                O[ni] = MFMA16(pf0, vf0[ni], O[ni]);
                O[ni] = MFMA16(pf1, vf1[ni], O[ni]);
            }
        }

#pragma unroll
        for (int r = 0; r < 4; r++) {
            float lt = ll[r];
            lt += __shfl_xor(lt, 1);
            lt += __shfl_xor(lt, 2);
            lt += __shfl_xor(lt, 4);
            lt += __shfl_xor(lt, 8);
            const int tg = trow_base + r;
            const float inv = g / lt;
#pragma unroll
            for (int ni = 0; ni < 4; ni++)
                attm[(size_t)(tg * 2 + b) * 1024 + h * 64 + ni * 16 + l16] = O[ni][r] * inv;
        }
    }
}

// ---------------------------------------------------------------------------
// att = attl + attm (gate already applied in the attn epilogues), f32 -> bf16.
// ---------------------------------------------------------------------------
__global__ __launch_bounds__(256) void combine_kernel(
    const float4* __restrict__ a, const float4* __restrict__ bsrc,
    bf16_t* __restrict__ o, int n4)
{
    const int i = blockIdx.x * 256 + threadIdx.x;
    if (i >= n4) return;
    const float4 x = a[i];
    const float4 y = bsrc[i];
    bf16x4 r;
    r[0] = (bf16_t)(x.x + y.x);
    r[1] = (bf16_t)(x.y + y.y);
    r[2] = (bf16_t)(x.z + y.z);
    r[3] = (bf16_t)(x.w + y.w);
    *(bf16x4*)(o + (size_t)i * 4) = r;
}

// ---------------------------------------------------------------------------
// Final output projection (unchanged).
// ---------------------------------------------------------------------------
__global__ __launch_bounds__(256) void gemm64_kernel(
    const bf16_t* __restrict__ X, const void* __restrict__ Wv,
    const void* __restrict__ biasv, void* __restrict__ Yv,
    const int* __restrict__ flag)
{
    __shared__ __attribute__((aligned(16))) bf16_t As[64 * 40];
    __shared__ __attribute__((aligned(16))) bf16_t Bs[128 * 40];

    const int f32 = flag[0];
    const int K = 1024, N = 1024;
    const int tid = threadIdx.x;
    const int wvid = tid >> 6, lane = tid & 63;
    const int qd = lane >> 4, l16 = lane & 15;
    const int wn = wvid * 32;
    const int rm0 = blockIdx.x * 64, cn0 = blockIdx.y * 128;

    const int arow = tid >> 1;
    const int aseg = (tid & 1) * 16;
    const bf16_t* Xp = X + (size_t)(rm0 + (arow & 63)) * K + aseg;
    const size_t woff = (size_t)(cn0 + arow) * K + aseg;
    const bf16_t* Wh = (const bf16_t*)Wv + woff;
    const float*  Wf = (const float*)Wv + woff;

    floatx4 acc[4][2];
#pragma unroll
    for (int i = 0; i < 4; i++)
#pragma unroll
        for (int j = 0; j < 2; j++) acc[i][j] = (floatx4){0.f, 0.f, 0.f, 0.f};

    for (int k0 = 0; k0 < K; k0 += 32) {
        bf16x8 x0, x1, w0, w1;
        if (tid < 128) {
            x0 = *(const bf16x8*)(Xp + k0);
            x1 = *(const bf16x8*)(Xp + k0 + 8);
        }
        if (f32) cvt16_f32(Wf + k0, w0, w1);
        else {
            w0 = *(const bf16x8*)(Wh + k0);
            w1 = *(const bf16x8*)(Wh + k0 + 8);
        }
        __syncthreads();
        if (tid < 128) {
            *(bf16x8*)&As[arow * 40 + aseg] = x0;
            *(bf16x8*)&As[arow * 40 + aseg + 8] = x1;
        }
        *(bf16x8*)&Bs[arow * 40 + aseg] = w0;
        *(bf16x8*)&Bs[arow * 40 + aseg + 8] = w1;
        __syncthreads();

        bf16x8 af[4], bfg[2];
#pragma unroll
        for (int mi = 0; mi < 4; mi++)
            af[mi] = *(const bf16x8*)(&As[(mi * 16 + l16) * 40 + qd * 8]);
#pragma unroll
        for (int ni = 0; ni < 2; ni++)
            bfg[ni] = *(const bf16x8*)(&Bs[(wn + ni * 16 + l16) * 40 + qd * 8]);
#pragma unroll
        for (int mi = 0; mi < 4; mi++)
#pragma unroll
            for (int ni = 0; ni < 2; ni++)
                acc[mi][ni] = MFMA16(af[mi], bfg[ni], acc[mi][ni]);
    }

#pragma unroll
    for (int ni = 0; ni < 2; ni++) {
        const int col = cn0 + wn + ni * 16 + l16;
        const float bv = f32 ? ((const float*)biasv)[col]
                             : (float)((const bf16_t*)biasv)[col];
#pragma unroll
        for (int mi = 0; mi < 4; mi++) {
            const int row0 = rm0 + mi * 16 + qd * 4;
#pragma unroll
            for (int r = 0; r < 4; r++) {
                const int row = row0 + r;
                const float val = acc[mi][ni][r] + bv;
                if (f32) ((float*)Yv)[(size_t)row * N + col] = val;
                else ((bf16_t*)Yv)[(size_t)row * N + col] = (bf16_t)val;
            }
        }
    }
}

__global__ void sentinel_kernel(float* o) { o[0] = 30000.0f; }

extern "C" void kernel_launch(void* const* d_in, const int* in_sizes, int n_in,
                              void* d_out, int out_size, void* d_ws, size_t ws_size,
                              hipStream_t stream)
{
    const void* query = d_in[0];
    const void* pos   = d_in[1];
    const void* lcr   = d_in[2];
    const void* q_w   = d_in[3];
    const void* q_b   = d_in[4];
    const void* k_w   = d_in[5];
    const void* k_b   = d_in[6];
    const void* v_w   = d_in[7];
    const void* v_b   = d_in[8];
    const void* out_w = d_in[9];
    const void* out_b = d_in[10];
    const void* mbias = d_in[11];

    const int T = 2048, B = 2, E = 1024, M = 1024;

    const size_t nqkv = (size_t)B * 16 * T * 64;   // 4,194,304
    const size_t nmem = (size_t)B * 16 * M * 64;   // 2,097,152
    const size_t natt = (size_t)T * B * E;         // 4,194,304
    const size_t bf16_elems = 3 * nqkv + 2 * nmem + natt;
    const size_t needed = bf16_elems * 2 + 2 * natt * 4 + 64;
    if (ws_size < needed) {
        sentinel_kernel<<<1, 1, 0, stream>>>((float*)d_out);
        return;
    }

    bf16_t* q_ws   = (bf16_t*)d_ws;
    bf16_t* k_ws   = q_ws + nqkv;
    bf16_t* vt_ws  = k_ws + nqkv;     // [B,H,64,T]
    bf16_t* km_ws  = vt_ws + nqkv;
    bf16_t* vmt_ws = km_ws + nmem;    // [B,H,64,M]
    bf16_t* att_ws = vmt_ws + nmem;   // bf16 combined attention output
    float* attl_ws = (float*)(att_ws + natt);
    float* attm_ws = attl_ws + natt;
    int* flag = (int*)(attm_ws + natt);

    detect_kernel<<<1, 1024, 0, stream>>>((const uint4*)query, flag);
    proj_kernel<<<1024, 256, 0, stream>>>(query, lcr, q_w, k_w, v_w,
                                          q_b, k_b, v_b,
                                          q_ws, k_ws, vt_ws, km_ws, vmt_ws, flag);
    attn_kernel<<<dim3(T / 64, 32, 2), 256, 0, stream>>>(
        q_ws, k_ws, vt_ws, km_ws, vmt_ws, pos, mbias, attl_ws, attm_ws, flag, T, M);
    combine_kernel<<<(int)(natt / 4 / 256), 256, 0, stream>>>(
        (const float4*)attl_ws, (const float4*)attm_ws, att_ws, (int)(natt / 4));
    gemm64_kernel<<<dim3(T * B / 64, E / 128), 256, 0, stream>>>(
        att_ws, out_w, out_b, d_out, flag);
    (void)in_sizes; (void)n_in; (void)out_size;
}

// Round 3
// 795.470 us; speedup vs baseline: 1.1113x; 1.0707x over previous
//
#include <hip/hip_runtime.h>

typedef __bf16 bf16_t;
typedef __bf16 bf16x2 __attribute__((ext_vector_type(2)));
typedef __bf16 bf16x4 __attribute__((ext_vector_type(4)));
typedef __bf16 bf16x8 __attribute__((ext_vector_type(8)));
typedef float floatx4 __attribute__((ext_vector_type(4)));

#define MFMA16(a, b, c) __builtin_amdgcn_mfma_f32_16x16x32_bf16((a), (b), (c), 0, 0, 0)

__global__ void detect_kernel(const uint4* __restrict__ q, int* __restrict__ flag)
{
    __shared__ int cnt;
    if (threadIdx.x == 0) cnt = 0;
    __syncthreads();
    int local = 0;
    // 65536 u16 = 8192 uint4
    for (int i = threadIdx.x; i < 8192; i += 1024) {
        uint4 u = q[i];
        unsigned w;
        w = u.x; if ((w & 0x7F80u) == 0x7F80u) local++; if (((w >> 16) & 0x7F80u) == 0x7F80u) local++;
        w = u.y; if ((w & 0x7F80u) == 0x7F80u) local++; if (((w >> 16) & 0x7F80u) == 0x7F80u) local++;
        w = u.z; if ((w & 0x7F80u) == 0x7F80u) local++; if (((w >> 16) & 0x7F80u) == 0x7F80u) local++;
        w = u.w; if ((w & 0x7F80u) == 0x7F80u) local++; if (((w >> 16) & 0x7F80u) == 0x7F80u) local++;
    }
    atomicAdd(&cnt, local);
    __syncthreads();
    if (threadIdx.x == 0) flag[0] = (cnt >= 8) ? 1 : 0;
}

__device__ inline void cvt16_f32(const float* __restrict__ p, bf16x8& lo, bf16x8& hi)
{
    float4 a = ((const float4*)p)[0];
    float4 b = ((const float4*)p)[1];
    float4 c = ((const float4*)p)[2];
    float4 d = ((const float4*)p)[3];
    lo[0] = (bf16_t)a.x; lo[1] = (bf16_t)a.y; lo[2] = (bf16_t)a.z; lo[3] = (bf16_t)a.w;
    lo[4] = (bf16_t)b.x; lo[5] = (bf16_t)b.y; lo[6] = (bf16_t)b.z; lo[7] = (bf16_t)b.w;
    hi[0] = (bf16_t)c.x; hi[1] = (bf16_t)c.y; hi[2] = (bf16_t)c.z; hi[3] = (bf16_t)c.w;
    hi[4] = (bf16_t)d.x; hi[5] = (bf16_t)d.y; hi[6] = (bf16_t)d.z; hi[7] = (bf16_t)d.w;
}

// ---------------------------------------------------------------------------
// Pos tiling: pack the causal tiles of position_encoding into bf16 tiles in
// MFMA C-fragment order, mask baked into diagonal tiles. Tile (h, qt, st)
// (st <= qt) stored at ((h*528 + qt*(qt+1)/2 + st) * 4096) bf16; within the
// tile, element ((g*16 + l16)*16 + ni*4 + r) = pos[h][qt*64 + g*4 + r]
//                                                 [st*64 + ni*16 + l16].
// The attn wave then reads 32 contiguous bytes per lane (2 KB/wave/iter).
// ---------------------------------------------------------------------------
__global__ __launch_bounds__(256) void prep_pos(
    const void* __restrict__ posv, bf16_t* __restrict__ post,
    const int* __restrict__ flag, int T)
{
    const int st = blockIdx.x, qt = blockIdx.y, h = blockIdx.z;
    if (st > qt) return;
    __shared__ float tf[64 * 65];
    const int t = threadIdx.x;
    const int f32 = flag[0];
    const size_t rb = ((size_t)h * T + qt * 64) * T + st * 64;
    if (f32) {
        const float* pf = (const float*)posv + rb;
#pragma unroll
        for (int it = 0; it < 4; ++it) {
            const int idx = it * 256 + t;          // 0..1023
            const int row = idx >> 4, c4 = (idx & 15) * 4;
            const float4 v = *(const float4*)(pf + (size_t)row * T + c4);
            tf[row * 65 + c4 + 0] = v.x;
            tf[row * 65 + c4 + 1] = v.y;
            tf[row * 65 + c4 + 2] = v.z;
            tf[row * 65 + c4 + 3] = v.w;
        }
    } else {
        const bf16_t* ph = (const bf16_t*)posv + rb;
#pragma unroll
        for (int it = 0; it < 2; ++it) {
            const int idx = it * 256 + t;          // 0..511
            const int row = idx >> 3, c8 = (idx & 7) * 8;
            const bf16x8 v = *(const bf16x8*)(ph + (size_t)row * T + c8);
#pragma unroll
            for (int j = 0; j < 8; ++j) tf[row * 65 + c8 + j] = (float)v[j];
        }
    }
    __syncthreads();
    const int gg = t >> 4, l16 = t & 15;
    const bool diag = (st == qt);
    bf16x8 o0, o1;
#pragma unroll
    for (int j = 0; j < 16; ++j) {
        const int ni = j >> 2, r = j & 3;
        const int row = gg * 4 + r, col = ni * 16 + l16;
        float v = tf[row * 65 + col];
        if (diag && col > row) v = -1e9f;
        if (j < 8) o0[j] = (bf16_t)v; else o1[j - 8] = (bf16_t)v;
    }
    bf16_t* out = post + ((size_t)h * 528 + (size_t)qt * (qt + 1) / 2 + st) * 4096
                       + (size_t)t * 16;
    *(bf16x8*)out = o0;
    *(bf16x8*)(out + 8) = o1;
}

// ---------------------------------------------------------------------------
// Merged projection GEMM (unchanged).
// ---------------------------------------------------------------------------
__global__ __launch_bounds__(256) void proj_kernel(
    const void* __restrict__ query, const void* __restrict__ lcr,
    const void* __restrict__ qw, const void* __restrict__ kw,
    const void* __restrict__ vw,
    const void* __restrict__ qbias, const void* __restrict__ kbias,
    const void* __restrict__ vbias,
    bf16_t* __restrict__ q_ws, bf16_t* __restrict__ k_ws,
    bf16_t* __restrict__ vt_ws, bf16_t* __restrict__ km_ws,
    bf16_t* __restrict__ vmt_ws, const int* __restrict__ flag)
{
    __shared__ __attribute__((aligned(16))) bf16_t As[128 * 40];
    __shared__ __attribute__((aligned(16))) bf16_t Bs[128 * 40];

    const int f32 = flag[0];
    const int K = 1024;
    const int blk = blockIdx.x;

    int rm0, wcol, mode, Tdim;
    float scale;
    const void* Xv; size_t xoff0; const void* Wv; const void* biasv; bf16_t* Yv;
    if (blk < 768) {
        rm0 = (blk & 31) * 128;
        const int cn0 = (blk >> 5) * 128;
        const int sel = cn0 >> 10;
        wcol = cn0 & 1023;
        Xv = query; xoff0 = 0; Tdim = 2048;
        if (sel == 0)      { Wv = qw; biasv = qbias; Yv = q_ws;  mode = 1; scale = 0.125f; }
        else if (sel == 1) { Wv = kw; biasv = kbias; Yv = k_ws;  mode = 1; scale = 1.f; }
        else               { Wv = vw; biasv = vbias; Yv = vt_ws; mode = 2; scale = 1.f; }
    } else if (blk < 896) {
        const int b2 = blk - 768;
        rm0 = (b2 & 15) * 128; wcol = (b2 >> 4) * 128;
        Xv = lcr; xoff0 = 0;
        Wv = kw; biasv = kbias; Yv = km_ws; mode = 1; scale = 1.f; Tdim = 1024;
    } else {
        const int b2 = blk - 896;
        rm0 = (b2 & 15) * 128; wcol = (b2 >> 4) * 128;
        Xv = lcr; xoff0 = (size_t)1024 * 2 * 1024;
        Wv = vw; biasv = vbias; Yv = vmt_ws; mode = 2; scale = 1.f; Tdim = 1024;
    }

    const int tid = threadIdx.x;
    const int wvid = tid >> 6, lane = tid & 63;
    const int qd = lane >> 4, l16 = lane & 15;
    const int wm = (wvid >> 1) * 64, wn = (wvid & 1) * 64;

    const int srow = tid >> 1;
    const int sseg = (tid & 1) * 16;
    const size_t xoff = xoff0 + (size_t)(rm0 + srow) * K + sseg;
    const size_t woff = (size_t)(wcol + srow) * K + sseg;
    const bf16_t* Xh = (const bf16_t*)Xv + xoff;
    const float*  Xf = (const float*)Xv + xoff;
    const bf16_t* Wh = (const bf16_t*)Wv + woff;
    const float*  Wf = (const float*)Wv + woff;
    bf16_t* Asw = &As[srow * 40 + sseg];
    bf16_t* Bsw = &Bs[srow * 40 + sseg];

    floatx4 acc[4][4];
#pragma unroll
    for (int i = 0; i < 4; i++)
#pragma unroll
        for (int j = 0; j < 4; j++) acc[i][j] = (floatx4){0.f, 0.f, 0.f, 0.f};

    for (int k0 = 0; k0 < K; k0 += 32) {
        bf16x8 x0, x1, w0, w1;
        if (f32) {
            cvt16_f32(Xf + k0, x0, x1);
            cvt16_f32(Wf + k0, w0, w1);
        } else {
            x0 = *(const bf16x8*)(Xh + k0);
            x1 = *(const bf16x8*)(Xh + k0 + 8);
            w0 = *(const bf16x8*)(Wh + k0);
            w1 = *(const bf16x8*)(Wh + k0 + 8);
        }
        __syncthreads();
        *(bf16x8*)(Asw) = x0;
        *(bf16x8*)(Asw + 8) = x1;
        *(bf16x8*)(Bsw) = w0;
        *(bf16x8*)(Bsw + 8) = w1;
        __syncthreads();

        bf16x8 af[4], bfg[4];
#pragma unroll
        for (int mi = 0; mi < 4; mi++)
            af[mi] = *(const bf16x8*)(&As[(wm + mi * 16 + l16) * 40 + qd * 8]);
#pragma unroll
        for (int ni = 0; ni < 4; ni++)
            bfg[ni] = *(const bf16x8*)(&Bs[(wn + ni * 16 + l16) * 40 + qd * 8]);
#pragma unroll
        for (int mi = 0; mi < 4; mi++)
#pragma unroll
            for (int ni = 0; ni < 4; ni++)
                acc[mi][ni] = MFMA16(af[mi], bfg[ni], acc[mi][ni]);
    }

#pragma unroll
    for (int ni = 0; ni < 4; ni++) {
        const int col = wcol + wn + ni * 16 + l16;
        const float bv = f32 ? ((const float*)biasv)[col]
                             : (float)((const bf16_t*)biasv)[col];
        const int hh = col >> 6, dd = col & 63;
#pragma unroll
        for (int mi = 0; mi < 4; mi++) {
            const int row0 = rm0 + wm + mi * 16 + qd * 4;  // always even
            const int t = row0 >> 1;                       // rows: (t,b=0),(t,1),(t+1,0),(t+1,1)
            const float v0 = (acc[mi][ni][0] + bv) * scale;
            const float v1 = (acc[mi][ni][1] + bv) * scale;
            const float v2 = (acc[mi][ni][2] + bv) * scale;
            const float v3 = (acc[mi][ni][3] + bv) * scale;
            if (mode == 1) {
                Yv[(((size_t)hh * Tdim) + t) * 64 + dd]            = (bf16_t)v0;
                Yv[(((size_t)(16 + hh) * Tdim) + t) * 64 + dd]     = (bf16_t)v1;
                Yv[(((size_t)hh * Tdim) + t + 1) * 64 + dd]        = (bf16_t)v2;
                Yv[(((size_t)(16 + hh) * Tdim) + t + 1) * 64 + dd] = (bf16_t)v3;
            } else {
                bf16x2 p0; p0[0] = (bf16_t)v0; p0[1] = (bf16_t)v2;
                bf16x2 p1; p1[0] = (bf16_t)v1; p1[1] = (bf16_t)v3;
                *(bf16x2*)&Yv[((size_t)hh * 64 + dd) * Tdim + t] = p0;
                *(bf16x2*)&Yv[((size_t)(16 + hh) * 64 + dd) * Tdim + t] = p1;
            }
        }
    }
}

// ---------------------------------------------------------------------------
// Flash attention, pair-balanced: block (p, y, z) handles query tiles
// qt = p and qt = 31-p sequentially (uniform 33 iters for z=0 local pass,
// 32 for z=1 memory pass). Pos read from packed bf16 tiles (mask baked)
// when tiled=1; direct dual-dtype gather fallback otherwise.
// ---------------------------------------------------------------------------
#define PSTR 88

__device__ __forceinline__ void load_k8(bf16x8 k0v[4], bf16x8 k1v[4],
                                        const bf16_t* __restrict__ Kb,
                                        int s0, int l16, int qd)
{
#pragma unroll
    for (int ni = 0; ni < 4; ni++) {
        const bf16_t* p = Kb + (size_t)(s0 + ni * 16 + l16) * 64 + qd * 8;
        k0v[ni] = *(const bf16x8*)p;
        k1v[ni] = *(const bf16x8*)(p + 32);
    }
}

__device__ __forceinline__ void load_pos4(floatx4 pn[4], const float* __restrict__ posf,
                                          const bf16_t* __restrict__ posh, int f32,
                                          int T, int trow_base, int s0, int l16, bool diag)
{
#pragma unroll
    for (int ni = 0; ni < 4; ni++) {
        const int sg = s0 + ni * 16 + l16;
#pragma unroll
        for (int r = 0; r < 4; r++) {
            const int tg = trow_base + r;
            const size_t pidx = (size_t)tg * T + sg;
            float pv = f32 ? posf[pidx] : (float)posh[pidx];
            if (diag && sg > tg) pv = -1e9f;
            pn[ni][r] = pv;
        }
    }
}

__global__ __launch_bounds__(256) void attn_kernel(
    const bf16_t* __restrict__ Qg, const bf16_t* __restrict__ Kg,
    const bf16_t* __restrict__ VTg, const bf16_t* __restrict__ KMg,
    const bf16_t* __restrict__ VMTg, const void* __restrict__ posv,
    const bf16_t* __restrict__ post, const void* __restrict__ mbiasv,
    float* __restrict__ attl, float* __restrict__ attm,
    const int* __restrict__ flag, int T, int Mlen, int tiled)
{
    __shared__ __attribute__((aligned(16))) bf16_t Ps[4][16 * PSTR];

    const int f32 = flag[0];
    const int tid = threadIdx.x;
    const int wv = tid >> 6, lane = tid & 63;
    const int qd = lane >> 4, l16 = lane & 15;
    const int p = blockIdx.x;
    const int y = blockIdx.y;
    const int b = y & 1, h = y >> 1;
    const int bh = b * 16 + h;
    bf16_t* Pw = &Ps[wv][0];
    const int laneTileOff = ((wv * 4 + qd) * 16 + l16) * 16;

    const float gb = f32 ? ((const float*)mbiasv)[h] : (float)((const bf16_t*)mbiasv)[h];
    const float g = 1.f / (1.f + __expf(-gb));
    const float gl = 1.f - g;

    const bf16_t* Qb = Qg + (size_t)bh * T * 64;

    for (int half = 0; half < 2; ++half) {
        const int qt = half ? (31 - p) : p;
        const int tw = qt * 64 + wv * 16;
        const int trow_base = tw + qd * 4;

        const bf16x8 a0 = *(const bf16x8*)(Qb + (size_t)(tw + l16) * 64 + qd * 8);
        const bf16x8 a1 = *(const bf16x8*)(Qb + (size_t)(tw + l16) * 64 + 32 + qd * 8);

        floatx4 O[4];
        float ml[4], ll[4];
#pragma unroll
        for (int i = 0; i < 4; i++) {
            O[i] = (floatx4){0.f, 0.f, 0.f, 0.f};
            ml[i] = -1e9f; ll[i] = 0.f;
        }

        bf16x8 kc0[4], kc1[4];

        if (blockIdx.z == 0) {
            // ---- local causal attention + position encoding ----
            const bf16_t* Kb  = Kg  + (size_t)bh * T * 64;
            const bf16_t* VTb = VTg + (size_t)bh * 64 * T;
            const float*  posf = (const float*)posv + (size_t)h * T * T;
            const bf16_t* posh = (const bf16_t*)posv + (size_t)h * T * T;
            const bf16_t* ptile = post + ((size_t)h * 528 + (size_t)qt * (qt + 1) / 2) * 4096
                                       + laneTileOff;

            floatx4 pn[4];
            bf16x8 pt0, pt1;
            load_k8(kc0, kc1, Kb, 0, l16, qd);
            if (tiled) {
                pt0 = *(const bf16x8*)(ptile);
                pt1 = *(const bf16x8*)(ptile + 8);
            } else {
                load_pos4(pn, posf, posh, f32, T, trow_base, 0, l16, qt == 0);
            }

            for (int st = 0; st <= qt; ++st) {
                const int s0 = st * 64;
                // V for this key block: issued now, consumed after softmax.
                bf16x8 vf0[4], vf1[4];
#pragma unroll
                for (int ni = 0; ni < 4; ni++) {
                    const bf16_t* vp = VTb + (size_t)(ni * 16 + l16) * T + s0 + qd * 8;
                    vf0[ni] = *(const bf16x8*)vp;
                    vf1[ni] = *(const bf16x8*)(vp + 32);
                }
                if (tiled) {
#pragma unroll
                    for (int ni = 0; ni < 4; ni++)
#pragma unroll
                        for (int r = 0; r < 4; r++)
                            pn[ni][r] = (ni < 2) ? (float)pt0[ni * 4 + r]
                                                 : (float)pt1[ni * 4 + r - 8];
                }
                // QK^T with pos (mask baked for diagonal tiles) as C-init.
                floatx4 c[4];
#pragma unroll
                for (int ni = 0; ni < 4; ni++) {
                    floatx4 t = pn[ni];
                    t = MFMA16(a0, kc0[ni], t);
                    t = MFMA16(a1, kc1[ni], t);
                    c[ni] = t;
                }
                // Prefetch K + pos for next key block.
                if (st < qt) {
                    load_k8(kc0, kc1, Kb, s0 + 64, l16, qd);
                    if (tiled) {
                        pt0 = *(const bf16x8*)(ptile + (st + 1) * 4096);
                        pt1 = *(const bf16x8*)(ptile + (st + 1) * 4096 + 8);
                    } else {
                        load_pos4(pn, posf, posh, f32, T, trow_base, s0 + 64, l16,
                                  st + 1 == qt);
                    }
                }
                // Online softmax (denominator kept per-lane, reduced at end).
#pragma unroll
                for (int r = 0; r < 4; r++) {
                    float mt = fmaxf(fmaxf(c[0][r], c[1][r]), fmaxf(c[2][r], c[3][r]));
                    mt = fmaxf(mt, __shfl_xor(mt, 1));
                    mt = fmaxf(mt, __shfl_xor(mt, 2));
                    mt = fmaxf(mt, __shfl_xor(mt, 4));
                    mt = fmaxf(mt, __shfl_xor(mt, 8));
                    const float mnew = fmaxf(ml[r], mt);
                    const float alpha = __expf(ml[r] - mnew);
                    ml[r] = mnew;
                    float ls = 0.f;
#pragma unroll
                    for (int ni = 0; ni < 4; ni++) {
                        const float pe = __expf(c[ni][r] - mnew);
                        c[ni][r] = pe;
                        ls += pe;
                    }
                    ll[r] = ll[r] * alpha + ls;
#pragma unroll
                    for (int ni = 0; ni < 4; ni++) O[ni][r] *= alpha;
#pragma unroll
                    for (int ni = 0; ni < 4; ni++)
                        Pw[(qd * 4 + r) * PSTR + ni * 16 + l16] = (bf16_t)c[ni][r];
                }
                asm volatile("s_waitcnt lgkmcnt(0)" ::: "memory");
                const bf16x8 pf0 = *(const bf16x8*)(&Pw[l16 * PSTR + qd * 8]);
                const bf16x8 pf1 = *(const bf16x8*)(&Pw[l16 * PSTR + 32 + qd * 8]);
#pragma unroll
                for (int ni = 0; ni < 4; ni++) {
                    O[ni] = MFMA16(pf0, vf0[ni], O[ni]);
                    O[ni] = MFMA16(pf1, vf1[ni], O[ni]);
                }
            }

#pragma unroll
            for (int r = 0; r < 4; r++) {
                float lt = ll[r];
                lt += __shfl_xor(lt, 1);
                lt += __shfl_xor(lt, 2);
                lt += __shfl_xor(lt, 4);
                lt += __shfl_xor(lt, 8);
                const int tg = trow_base + r;
                const float inv = gl / lt;
#pragma unroll
                for (int ni = 0; ni < 4; ni++)
                    attl[(size_t)(tg * 2 + b) * 1024 + h * 64 + ni * 16 + l16] = O[ni][r] * inv;
            }
        } else {
            // ---- memory attention (no mask, no pos) ----
            const bf16_t* Kb  = KMg  + (size_t)bh * Mlen * 64;
            const bf16_t* VTb = VMTg + (size_t)bh * 64 * Mlen;
            const int nst = Mlen >> 6;

            load_k8(kc0, kc1, Kb, 0, l16, qd);

            for (int st = 0; st < nst; ++st) {
                const int s0 = st * 64;
                bf16x8 vf0[4], vf1[4];
#pragma unroll
                for (int ni = 0; ni < 4; ni++) {
                    const bf16_t* vp = VTb + (size_t)(ni * 16 + l16) * Mlen + s0 + qd * 8;
                    vf0[ni] = *(const bf16x8*)vp;
                    vf1[ni] = *(const bf16x8*)(vp + 32);
                }
                floatx4 c[4];
#pragma unroll
                for (int ni = 0; ni < 4; ni++) {
                    floatx4 t = (floatx4){0.f, 0.f, 0.f, 0.f};
                    t = MFMA16(a0, kc0[ni], t);
                    t = MFMA16(a1, kc1[ni], t);
                    c[ni] = t;
                }
                if (st < nst - 1) load_k8(kc0, kc1, Kb, s0 + 64, l16, qd);
#pragma unroll
                for (int r = 0; r < 4; r++) {
                    float mt = fmaxf(fmaxf(c[0][r], c[1][r]), fmaxf(c[2][r], c[3][r]));
                    mt = fmaxf(mt, __shfl_xor(mt, 1));
                    mt = fmaxf(mt, __shfl_xor(mt, 2));
                    mt = fmaxf(mt, __shfl_xor(mt, 4));
                    mt = fmaxf(mt, __shfl_xor(mt, 8));
                    const float mnew = fmaxf(ml[r], mt);
                    const float alpha = __expf(ml[r] - mnew);
                    ml[r] = mnew;
                    float ls = 0.f;
#pragma unroll
                    for (int ni = 0; ni < 4; ni++) {
                        const float pe = __expf(c[ni][r] - mnew);
                        c[ni][r] = pe;
                        ls += pe;
                    }
                    ll[r] = ll[r] * alpha + ls;
#pragma unroll
                    for (int ni = 0; ni < 4; ni++) O[ni][r] *= alpha;
#pragma unroll
                    for (int ni = 0; ni < 4; ni++)
                        Pw[(qd * 4 + r) * PSTR + ni * 16 + l16] = (bf16_t)c[ni][r];
                }
                asm volatile("s_waitcnt lgkmcnt(0)" ::: "memory");
                const bf16x8 pf0 = *(const bf16x8*)(&Pw[l16 * PSTR + qd * 8]);
                const bf16x8 pf1 = *(const bf16x8*)(&Pw[l16 * PSTR + 32 + qd * 8]);
#pragma unroll
                for (int ni = 0; ni < 4; ni++) {
                    O[ni] = MFMA16(pf0, vf0[ni], O[ni]);
                    O[ni] = MFMA16(pf1, vf1[ni], O[ni]);
                }
            }

#pragma unroll
            for (int r = 0; r < 4; r++) {
                float lt = ll[r];
                lt += __shfl_xor(lt, 1);
                lt += __shfl_xor(lt, 2);
                lt += __shfl_xor(lt, 4);
                lt += __shfl_xor(lt, 8);
                const int tg = trow_base + r;
                const float inv = g / lt;
#pragma unroll
                for (int ni = 0; ni < 4; ni++)
                    attm[(size_t)(tg * 2 + b) * 1024 + h * 64 + ni * 16 + l16] = O[ni][r] * inv;
            }
        }
    }
}

// ---------------------------------------------------------------------------
// att = attl + attm (gate already applied in the attn epilogues), f32 -> bf16.
// ---------------------------------------------------------------------------
__global__ __launch_bounds__(256) void combine_kernel(
    const float4* __restrict__ a, const float4* __restrict__ bsrc,
    bf16_t* __restrict__ o, int n4)
{
    const int i = blockIdx.x * 256 + threadIdx.x;
    if (i >= n4) return;
    const float4 x = a[i];
    const float4 y = bsrc[i];
    bf16x4 r;
    r[0] = (bf16_t)(x.x + y.x);
    r[1] = (bf16_t)(x.y + y.y);
    r[2] = (bf16_t)(x.z + y.z);
    r[3] = (bf16_t)(x.w + y.w);
    *(bf16x4*)(o + (size_t)i * 4) = r;
}

// ---------------------------------------------------------------------------
// Final output projection (unchanged).
// ---------------------------------------------------------------------------
__global__ __launch_bounds__(256) void gemm64_kernel(
    const bf16_t* __restrict__ X, const void* __restrict__ Wv,
    const void* __restrict__ biasv, void* __restrict__ Yv,
    const int* __restrict__ flag)
{
    __shared__ __attribute__((aligned(16))) bf16_t As[64 * 40];
    __shared__ __attribute__((aligned(16))) bf16_t Bs[128 * 40];

    const int f32 = flag[0];
    const int K = 1024, N = 1024;
    const int tid = threadIdx.x;
    const int wvid = tid >> 6, lane = tid & 63;
    const int qd = lane >> 4, l16 = lane & 15;
    const int wn = wvid * 32;
    const int rm0 = blockIdx.x * 64, cn0 = blockIdx.y * 128;

    const int arow = tid >> 1;
    const int aseg = (tid & 1) * 16;
    const bf16_t* Xp = X + (size_t)(rm0 + (arow & 63)) * K + aseg;
    const size_t woff = (size_t)(cn0 + arow) * K + aseg;
    const bf16_t* Wh = (const bf16_t*)Wv + woff;
    const float*  Wf = (const float*)Wv + woff;

    floatx4 acc[4][2];
#pragma unroll
    for (int i = 0; i < 4; i++)
#pragma unroll
        for (int j = 0; j < 2; j++) acc[i][j] = (floatx4){0.f, 0.f, 0.f, 0.f};

    for (int k0 = 0; k0 < K; k0 += 32) {
        bf16x8 x0, x1, w0, w1;
        if (tid < 128) {
            x0 = *(const bf16x8*)(Xp + k0);
            x1 = *(const bf16x8*)(Xp + k0 + 8);
        }
        if (f32) cvt16_f32(Wf + k0, w0, w1);
        else {
            w0 = *(const bf16x8*)(Wh + k0);
            w1 = *(const bf16x8*)(Wh + k0 + 8);
        }
        __syncthreads();
        if (tid < 128) {
            *(bf16x8*)&As[arow * 40 + aseg] = x0;
            *(bf16x8*)&As[arow * 40 + aseg + 8] = x1;
        }
        *(bf16x8*)&Bs[arow * 40 + aseg] = w0;
        *(bf16x8*)&Bs[arow * 40 + aseg + 8] = w1;
        __syncthreads();

        bf16x8 af[4], bfg[2];
#pragma unroll
        for (int mi = 0; mi < 4; mi++)
            af[mi] = *(const bf16x8*)(&As[(mi * 16 + l16) * 40 + qd * 8]);
#pragma unroll
        for (int ni = 0; ni < 2; ni++)
            bfg[ni] = *(const bf16x8*)(&Bs[(wn + ni * 16 + l16) * 40 + qd * 8]);
#pragma unroll
        for (int mi = 0; mi < 4; mi++)
#pragma unroll
            for (int ni = 0; ni < 2; ni++)
                acc[mi][ni] = MFMA16(af[mi], bfg[ni], acc[mi][ni]);
    }

#pragma unroll
    for (int ni = 0; ni < 2; ni++) {
        const int col = cn0 + wn + ni * 16 + l16;
        const float bv = f32 ? ((const float*)biasv)[col]
                             : (float)((const bf16_t*)biasv)[col];
#pragma unroll
        for (int mi = 0; mi < 4; mi++) {
            const int row0 = rm0 + mi * 16 + qd * 4;
#pragma unroll
            for (int r = 0; r < 4; r++) {
                const int row = row0 + r;
                const float val = acc[mi][ni][r] + bv;
                if (f32) ((float*)Yv)[(size_t)row * N + col] = val;
                else ((bf16_t*)Yv)[(size_t)row * N + col] = (bf16_t)val;
            }
        }
    }
}

__global__ void sentinel_kernel(float* o) { o[0] = 30000.0f; }

extern "C" void kernel_launch(void* const* d_in, const int* in_sizes, int n_in,
                              void* d_out, int out_size, void* d_ws, size_t ws_size,
                              hipStream_t stream)
{
    const void* query = d_in[0];
    const void* pos   = d_in[1];
    const void* lcr   = d_in[2];
    const void* q_w   = d_in[3];
    const void* q_b   = d_in[4];
    const void* k_w   = d_in[5];
    const void* k_b   = d_in[6];
    const void* v_w   = d_in[7];
    const void* v_b   = d_in[8];
    const void* out_w = d_in[9];
    const void* out_b = d_in[10];
    const void* mbias = d_in[11];

    const int T = 2048, B = 2, E = 1024, M = 1024;

    const size_t nqkv = (size_t)B * 16 * T * 64;   // 4,194,304
    const size_t nmem = (size_t)B * 16 * M * 64;   // 2,097,152
    const size_t natt = (size_t)T * B * E;         // 4,194,304
    const size_t bf16_elems = 3 * nqkv + 2 * nmem + natt;
    const size_t needed_small = bf16_elems * 2 + 2 * natt * 4 + 64;
    const size_t post_bytes = (size_t)16 * 528 * 4096 * 2;  // 69,206,016
    const size_t needed_tiled = needed_small + post_bytes;
    if (ws_size < needed_small) {
        sentinel_kernel<<<1, 1, 0, stream>>>((float*)d_out);
        return;
    }
    const int tiled = (ws_size >= needed_tiled) ? 1 : 0;

    bf16_t* q_ws   = (bf16_t*)d_ws;
    bf16_t* k_ws   = q_ws + nqkv;
    bf16_t* vt_ws  = k_ws + nqkv;     // [B,H,64,T]
    bf16_t* km_ws  = vt_ws + nqkv;
    bf16_t* vmt_ws = km_ws + nmem;    // [B,H,64,M]
    bf16_t* att_ws = vmt_ws + nmem;   // bf16 combined attention output
    float* attl_ws = (float*)(att_ws + natt);
    float* attm_ws = attl_ws + natt;
    int* flag = (int*)(attm_ws + natt);
    bf16_t* post_ws = (bf16_t*)((char*)d_ws + needed_small);

    detect_kernel<<<1, 1024, 0, stream>>>((const uint4*)query, flag);
    if (tiled)
        prep_pos<<<dim3(32, 32, 16), 256, 0, stream>>>(pos, post_ws, flag, T);
    proj_kernel<<<1024, 256, 0, stream>>>(query, lcr, q_w, k_w, v_w,
                                          q_b, k_b, v_b,
                                          q_ws, k_ws, vt_ws, km_ws, vmt_ws, flag);
    attn_kernel<<<dim3(16, 32, 2), 256, 0, stream>>>(
        q_ws, k_ws, vt_ws, km_ws, vmt_ws, pos, post_ws, mbias,
        attl_ws, attm_ws, flag, T, M, tiled);
    combine_kernel<<<(int)(natt / 4 / 256), 256, 0, stream>>>(
        (const float4*)attl_ws, (const float4*)attm_ws, att_ws, (int)(natt / 4));
    gemm64_kernel<<<dim3(T * B / 64, E / 128), 256, 0, stream>>>(
        att_ws, out_w, out_b, d_out, flag);
    (void)in_sizes; (void)n_in; (void)out_size;
}